// Round 1
// baseline (170.441 us; speedup 1.0000x reference)
//
#include <hip/hip_runtime.h>

typedef __attribute__((ext_vector_type(8))) short bf16x8;
typedef __attribute__((ext_vector_type(4))) float f32x4;

#define AS3 __attribute__((address_space(3)))
#define AS1 __attribute__((address_space(1)))

__device__ __forceinline__ unsigned short f2bf(float f) {
  unsigned u = __float_as_uint(f);
  u += 0x7fffu + ((u >> 16) & 1u);
  return (unsigned short)(u >> 16);
}

// ---------------- kernel 1: global average pool ----------------
// x viewed as [B*CIN][4096] -> pooled[B*CIN]
__global__ void pool_kernel(const float* __restrict__ x, float* __restrict__ pooled) {
  const int bc = blockIdx.x;
  const float4* p = reinterpret_cast<const float4*>(x) + (size_t)bc * 1024;
  float s = 0.f;
  for (int i = threadIdx.x; i < 1024; i += 256) {
    float4 v = p[i];
    s += v.x + v.y + v.z + v.w;
  }
#pragma unroll
  for (int off = 32; off > 0; off >>= 1) s += __shfl_xor(s, off, 64);
  __shared__ float wsum[4];
  if ((threadIdx.x & 63) == 0) wsum[threadIdx.x >> 6] = s;
  __syncthreads();
  if (threadIdx.x == 0)
    pooled[bc] = (wsum[0] + wsum[1] + wsum[2] + wsum[3]) * (1.0f / 4096.0f);
}

// ---------------- kernel 2: attention MLP + softmax ----------------
// pooled[16][256] -> att[16][4]
__global__ void attn_kernel(const float* __restrict__ pooled,
                            const float* __restrict__ w1,
                            const float* __restrict__ bng,
                            const float* __restrict__ bnb,
                            const float* __restrict__ bnm,
                            const float* __restrict__ bnv,
                            const float* __restrict__ w2,
                            float* __restrict__ att) {
  __shared__ float hbuf[256];
  const int t = threadIdx.x;
  const int b = t >> 4, i = t & 15;
  float s = 0.f;
  for (int c = 0; c < 256; ++c) s += pooled[b * 256 + c] * w1[i * 256 + c];
  float h = (s - bnm[i]) * rsqrtf(bnv[i] + 1e-5f) * bng[i] + bnb[i];
  hbuf[t] = fmaxf(h, 0.f);
  __syncthreads();
  if (t < 64) {
    const int bb = t >> 2, k = t & 3;
    float l = 0.f;
    for (int j = 0; j < 16; ++j) l += hbuf[bb * 16 + j] * w2[k * 16 + j];
    float m = l;
    m = fmaxf(m, __shfl_xor(m, 1, 64));
    m = fmaxf(m, __shfl_xor(m, 2, 64));
    float e = expf(l - m);
    float sum = e;
    sum += __shfl_xor(sum, 1, 64);
    sum += __shfl_xor(sum, 2, 64);
    att[bb * 4 + k] = e / sum;
  }
}

// ---------------- kernel 3: aggregate per-sample kernels ----------------
// weight[4][256][256][3][3] fp32, att[16][4] -> agg[b][tap][cout][cin] bf16
__global__ void agg_kernel(const float* __restrict__ att,
                           const float* __restrict__ wgt,
                           unsigned short* __restrict__ agg) {
  const int bo = blockIdx.x;
  const int b = bo >> 8, o = bo & 255;
  const int c = threadIdx.x;
  float acc[9];
#pragma unroll
  for (int t = 0; t < 9; ++t) acc[t] = 0.f;
#pragma unroll
  for (int k = 0; k < 4; ++k) {
    const float ak = att[b * 4 + k];
    const float* wp = wgt + ((size_t)((k << 8) + o) * 256 + c) * 9;
#pragma unroll
    for (int t = 0; t < 9; ++t) acc[t] += ak * wp[t];
  }
#pragma unroll
  for (int t = 0; t < 9; ++t)
    agg[(((size_t)(b * 9 + t) * 256) + o) * 256 + c] = f2bf(acc[t]);
}

// ---------------- kernel 4: transpose + pad + bf16 convert ----------------
// x[b][c][y][x] -> xTp[b][(y+1)*66+(x+1)][c] bf16 (borders pre-zeroed by memset)
__global__ void transpose_kernel(const float* __restrict__ x,
                                 unsigned short* __restrict__ xTp) {
  __shared__ unsigned short tb[64][258];
  const int blk = blockIdx.x;
  const int b = blk >> 6, y = blk & 63;
  const int t = threadIdx.x;
  const int xcol = t & 63;
  const int cbase = t >> 6;
  const float* src = x + (size_t)b * 256 * 4096 + (size_t)y * 64;
  for (int it = 0; it < 64; ++it) {
    const int c = it * 4 + cbase;
    tb[xcol][c] = f2bf(src[(size_t)c * 4096 + xcol]);
  }
  __syncthreads();
  unsigned short* dst = xTp + (size_t)b * (4356 * 256) + ((size_t)(y + 1) * 66 + 1) * 256;
  for (int xx = 0; xx < 64; ++xx) {
    dst[(size_t)xx * 256 + t] = tb[xx][t];
  }
}

// ---------------- kernel 5: per-sample implicit-GEMM conv (bf16 MFMA) ----
// per sample: D[p=4096][cout=256] = sum over 9 taps, K=256 channels
// A = xTp rows (p-major, cin contiguous), B^T = agg (cout-major, cin contiguous)
__global__ __launch_bounds__(256) void conv_kernel(
    const unsigned short* __restrict__ xTp,
    const unsigned short* __restrict__ agg,
    float* __restrict__ out) {
  __shared__ unsigned short ldsA[128 * 64];
  __shared__ unsigned short ldsB[128 * 64];

  const int bid = blockIdx.x;
  const int b = bid >> 6;
  const int rem = bid & 63;
  const int p0 = (rem >> 1) << 7;  // spatial tile base (multiple of 128)
  const int n0 = (rem & 1) << 7;   // cout tile base
  const int y0 = p0 >> 6;

  const int tid = threadIdx.x;
  const int lane = tid & 63;
  const int wave = tid >> 6;
  const int wm = (wave >> 1) << 6;
  const int wn = (wave & 1) << 6;

  // staging geometry: round i covers tile rows [i*32, i*32+32)
  int rr[4], swc[4];
  {
    const int strow = tid >> 3;
    const int scolb = (tid & 7) << 4;
#pragma unroll
    for (int i = 0; i < 4; ++i) {
      rr[i] = i * 32 + strow;
      // pre-swizzled SOURCE column (elements): involution byte ^= ((row&7)<<4)
      swc[i] = (scolb ^ ((rr[i] & 7) << 4)) >> 1;
    }
  }

  // fragment LDS byte offsets (swizzled reads), constant across K-loop
  const int l15 = lane & 15;
  const int lhi = lane >> 4;
  const int lsw = (lane & 7) << 4;
  int aoff[2][4], boff[2][4];
#pragma unroll
  for (int kk = 0; kk < 2; ++kk) {
#pragma unroll
    for (int m = 0; m < 4; ++m) {
      const int kb = ((kk << 6) + (lhi << 4)) ^ lsw;
      aoff[kk][m] = (wm + m * 16 + l15) * 128 + kb;
      boff[kk][m] = (wn + m * 16 + l15) * 128 + kb;
    }
  }

  const unsigned short* xb = xTp + (size_t)b * (4356 * 256);

  f32x4 acc[4][4];
#pragma unroll
  for (int m = 0; m < 4; ++m)
#pragma unroll
    for (int n = 0; n < 4; ++n) acc[m][n] = (f32x4){0.f, 0.f, 0.f, 0.f};

  AS3 char* ldsA3 = (AS3 char*)ldsA;
  AS3 char* ldsB3 = (AS3 char*)ldsB;

  for (int tap = 0; tap < 9; ++tap) {
    const int dy = tap / 3, dx = tap % 3;
    int srA[4], srB[4];
#pragma unroll
    for (int i = 0; i < 4; ++i) {
      const int yy = y0 + (rr[i] >> 6) + dy;
      const int xx = (rr[i] & 63) + dx;
      srA[i] = (yy * 66 + xx) * 256 + swc[i];
      srB[i] = (((b * 9 + tap) << 8) + n0 + rr[i]) * 256 + swc[i];
    }
#pragma unroll 1
    for (int c0 = 0; c0 < 256; c0 += 64) {
      __syncthreads();
#pragma unroll
      for (int i = 0; i < 4; ++i)
        __builtin_amdgcn_global_load_lds(
            (const AS1 void*)(xb + srA[i] + c0),
            (AS3 void*)(ldsA3 + (i << 12) + (wave << 10)), 16, 0, 0);
#pragma unroll
      for (int i = 0; i < 4; ++i)
        __builtin_amdgcn_global_load_lds(
            (const AS1 void*)(agg + srB[i] + c0),
            (AS3 void*)(ldsB3 + (i << 12) + (wave << 10)), 16, 0, 0);
      __syncthreads();
#pragma unroll
      for (int kk = 0; kk < 2; ++kk) {
        bf16x8 af[4], bfr[4];
#pragma unroll
        for (int m = 0; m < 4; ++m)
          af[m] = *reinterpret_cast<const bf16x8*>((const char*)ldsA + aoff[kk][m]);
#pragma unroll
        for (int n = 0; n < 4; ++n)
          bfr[n] = *reinterpret_cast<const bf16x8*>((const char*)ldsB + boff[kk][n]);
#pragma unroll
        for (int m = 0; m < 4; ++m)
#pragma unroll
          for (int n = 0; n < 4; ++n)
            acc[m][n] = __builtin_amdgcn_mfma_f32_16x16x32_bf16(af[m], bfr[n],
                                                                acc[m][n], 0, 0, 0);
      }
    }
  }

  // epilogue: D row=(lane>>4)*4+reg is p, col=lane&15 is cout
#pragma unroll
  for (int m = 0; m < 4; ++m) {
    const int p = p0 + wm + m * 16 + (lhi << 2);
#pragma unroll
    for (int n = 0; n < 4; ++n) {
      const int co = n0 + wn + n * 16 + l15;
      float* dst = out + ((size_t)(b * 256 + co) << 12) + p;
      *reinterpret_cast<f32x4*>(dst) = acc[m][n];
    }
  }
}

extern "C" void kernel_launch(void* const* d_in, const int* in_sizes, int n_in,
                              void* d_out, int out_size, void* d_ws, size_t ws_size,
                              hipStream_t stream) {
  const float* x = (const float*)d_in[0];
  const float* w1 = (const float*)d_in[1];
  const float* bng = (const float*)d_in[2];
  const float* bnb = (const float*)d_in[3];
  const float* bnm = (const float*)d_in[4];
  const float* bnv = (const float*)d_in[5];
  const float* w2 = (const float*)d_in[6];
  const float* wgt = (const float*)d_in[7];
  float* out = (float*)d_out;

  char* ws = (char*)d_ws;
  const size_t xtp_bytes = (size_t)16 * 4356 * 256 * 2;   // 35,684,352
  const size_t agg_bytes = (size_t)16 * 9 * 256 * 256 * 2; // 18,874,368
  unsigned short* xTp = (unsigned short*)ws;
  unsigned short* agg = (unsigned short*)(ws + xtp_bytes);
  float* pooled = (float*)(ws + xtp_bytes + agg_bytes);
  float* att = (float*)(ws + xtp_bytes + agg_bytes + 16384);

  hipMemsetAsync(xTp, 0, xtp_bytes, stream);
  pool_kernel<<<4096, 256, 0, stream>>>(x, pooled);
  attn_kernel<<<1, 256, 0, stream>>>(pooled, w1, bng, bnb, bnm, bnv, w2, att);
  agg_kernel<<<4096, 256, 0, stream>>>(att, wgt, agg);
  transpose_kernel<<<1024, 256, 0, stream>>>(x, xTp);
  conv_kernel<<<1024, 256, 0, stream>>>(xTp, agg, out);
}

// Round 2
// 126.884 us; speedup vs baseline: 1.3433x; 1.3433x over previous
//
#include <hip/hip_runtime.h>

typedef __attribute__((ext_vector_type(8))) short bf16x8;
typedef __attribute__((ext_vector_type(4))) float f32x4;

#define AS3 __attribute__((address_space(3)))
#define AS1 __attribute__((address_space(1)))

__device__ __forceinline__ unsigned short f2bf(float f) {
  unsigned u = __float_as_uint(f);
  u += 0x7fffu + ((u >> 16) & 1u);
  return (unsigned short)(u >> 16);
}

// ---------------- kernel 1: transpose + pad + bf16 convert + pooled partial sums
// x[b][c][y][x] -> xTp[b][(y+1)*66+(x+1)][c] bf16; atomicAdd channel sums into pooled
__global__ void transpose_kernel(const float* __restrict__ x,
                                 unsigned short* __restrict__ xTp,
                                 float* __restrict__ pooled) {
  __shared__ unsigned short tb[64][258];
  const int blk = blockIdx.x;
  const int b = blk >> 6, y = blk & 63;
  const int t = threadIdx.x;
  const int xcol = t & 63;
  const int cbase = t >> 6;
  const float* src = x + (size_t)b * 256 * 4096 + (size_t)y * 64;
  for (int it = 0; it < 64; ++it) {
    const int c = it * 4 + cbase;
    tb[xcol][c] = f2bf(src[(size_t)c * 4096 + xcol]);
  }
  __syncthreads();
  unsigned short* dst = xTp + (size_t)b * (4356 * 256) + ((size_t)(y + 1) * 66 + 1) * 256;
  float psum = 0.f;
  for (int xx = 0; xx < 64; ++xx) {
    const unsigned short v = tb[xx][t];
    psum += __uint_as_float((unsigned)v << 16);
    dst[(size_t)xx * 256 + t] = v;
  }
  atomicAdd(&pooled[b * 256 + t], psum * (1.0f / 4096.0f));
}

// ---------------- kernel 1b: zero the pad borders of xTp ----------------
__global__ void border_kernel(unsigned short* __restrict__ xTp) {
  const int br = blockIdx.x;  // 0..259
  const int b = blockIdx.y;
  int y, xx;
  if (br < 66) { y = 0; xx = br; }
  else if (br < 132) { y = 65; xx = br - 66; }
  else { const int k = br - 132; y = 1 + (k >> 1); xx = (k & 1) * 65; }
  xTp[((size_t)b * 4356 + y * 66 + xx) * 256 + threadIdx.x] = 0;
}

// ---------------- kernel 2: attention MLP + softmax ----------------
// pooled[16][256] -> att[16][4]
__global__ void attn_kernel(const float* __restrict__ pooled,
                            const float* __restrict__ w1,
                            const float* __restrict__ bng,
                            const float* __restrict__ bnb,
                            const float* __restrict__ bnm,
                            const float* __restrict__ bnv,
                            const float* __restrict__ w2,
                            float* __restrict__ att) {
  __shared__ float hbuf[256];
  const int t = threadIdx.x;
  const int b = t >> 4, i = t & 15;
  float s = 0.f;
  for (int c = 0; c < 256; ++c) s += pooled[b * 256 + c] * w1[i * 256 + c];
  float h = (s - bnm[i]) * rsqrtf(bnv[i] + 1e-5f) * bng[i] + bnb[i];
  hbuf[t] = fmaxf(h, 0.f);
  __syncthreads();
  if (t < 64) {
    const int bb = t >> 2, k = t & 3;
    float l = 0.f;
    for (int j = 0; j < 16; ++j) l += hbuf[bb * 16 + j] * w2[k * 16 + j];
    float m = l;
    m = fmaxf(m, __shfl_xor(m, 1, 64));
    m = fmaxf(m, __shfl_xor(m, 2, 64));
    float e = expf(l - m);
    float sum = e;
    sum += __shfl_xor(sum, 1, 64);
    sum += __shfl_xor(sum, 2, 64);
    att[bb * 4 + k] = e / sum;
  }
}

// ---------------- kernel 3: aggregate per-sample kernels ----------------
// weight[4][256][256][3][3] fp32, att[16][4] -> agg[b][tap][cout][cin] bf16
__global__ void agg_kernel(const float* __restrict__ att,
                           const float* __restrict__ wgt,
                           unsigned short* __restrict__ agg) {
  const int bo = blockIdx.x;
  const int b = bo >> 8, o = bo & 255;
  const int c = threadIdx.x;
  float acc[9];
#pragma unroll
  for (int t = 0; t < 9; ++t) acc[t] = 0.f;
#pragma unroll
  for (int k = 0; k < 4; ++k) {
    const float ak = att[b * 4 + k];
    const float* wp = wgt + ((size_t)((k << 8) + o) * 256 + c) * 9;
#pragma unroll
    for (int t = 0; t < 9; ++t) acc[t] += ak * wp[t];
  }
#pragma unroll
  for (int t = 0; t < 9; ++t)
    agg[(((size_t)(b * 9 + t) * 256) + o) * 256 + c] = f2bf(acc[t]);
}

// ---------------- kernel 4: per-sample implicit-GEMM conv (bf16 MFMA) ----
// 256x256 tile, BK=32, 8 waves (2Mx4N), ring-4 LDS, counted vmcnt(8),
// one barrier per K-tile, setprio around MFMA cluster.
__global__ __launch_bounds__(512, 2) void conv_kernel(
    const unsigned short* __restrict__ xTp,
    const unsigned short* __restrict__ agg,
    float* __restrict__ out) {
  __shared__ unsigned short ldsA[4 * 256 * 32];  // 64 KiB
  __shared__ unsigned short ldsB[4 * 256 * 32];  // 64 KiB

  const int bid = blockIdx.x;
  const int b = bid & 15;   // sample -> XCD = b%8 (same-sample blocks co-XCD)
  const int mt = bid >> 4;  // M-tile
  const int p0 = mt << 8;
  const int y0 = mt << 2;

  const int tid = threadIdx.x;
  const int lane = tid & 63;
  const int wave = tid >> 6;
  const int wm = wave >> 2;  // 0..1  (M half)
  const int wn = wave & 3;   // 0..3  (N quarter)

  // staging geometry: per issue, thread t covers row t>>2 (+128*issue), col (t&3)*8
  const int srow = tid >> 2;
  const int scol = (tid & 3) << 3;
  int baseA[2], baseB[2];
#pragma unroll
  for (int issue = 0; issue < 2; ++issue) {
    const int r = srow + (issue << 7);
    baseA[issue] = ((y0 + (r >> 6)) * 66 + (r & 63)) * 256 + scol;
    baseB[issue] = (b * 2304 + r) * 256 + scol;
  }

  const unsigned short* xb = xTp + (size_t)b * (4356 * 256);
  AS3 char* ldsA3 = (AS3 char*)ldsA;
  AS3 char* ldsB3 = (AS3 char*)ldsB;

  auto stage = [&](int ks_) {
    const int kss = ks_ > 71 ? 71 : ks_;  // clamp keeps vmcnt count uniform
    const int slotb = (ks_ & 3) << 14;    // slot from UNclamped index
    const int tap = kss >> 3;
    const int dy = tap / 3;
    const int dx = tap - dy * 3;
    const int c0 = (kss & 7) << 5;
    const int offA = (dy * 66 + dx) * 256 + c0;
    const int offB = (tap << 16) + c0;
#pragma unroll
    for (int issue = 0; issue < 2; ++issue) {
      __builtin_amdgcn_global_load_lds(
          (const AS1 void*)(xb + baseA[issue] + offA),
          (AS3 void*)(ldsA3 + slotb + (issue << 13) + (wave << 10)), 16, 0, 0);
      __builtin_amdgcn_global_load_lds(
          (const AS1 void*)(agg + baseB[issue] + offB),
          (AS3 void*)(ldsB3 + slotb + (issue << 13) + (wave << 10)), 16, 0, 0);
    }
  };

  // MFMA fragment LDS byte offsets (contiguous 1KiB per frag -> conflict-free)
  const int l15 = lane & 15;
  const int lhi = lane >> 4;
  int aoff[8], boff[4];
#pragma unroll
  for (int m = 0; m < 8; ++m) aoff[m] = (wm * 128 + m * 16 + l15) * 64 + lhi * 16;
#pragma unroll
  for (int n = 0; n < 4; ++n) boff[n] = (wn * 64 + n * 16 + l15) * 64 + lhi * 16;

  f32x4 acc[8][4];
#pragma unroll
  for (int m = 0; m < 8; ++m)
#pragma unroll
    for (int n = 0; n < 4; ++n) acc[m][n] = (f32x4){0.f, 0.f, 0.f, 0.f};

  stage(0);
  stage(1);
  stage(2);

#pragma unroll 1
  for (int ks = 0; ks < 72; ++ks) {
    // tile ks landed when <=8 of our loads outstanding (tiles ks+1, ks+2)
    asm volatile("s_waitcnt vmcnt(8)" ::: "memory");
    __builtin_amdgcn_s_barrier();   // all waves' loads landed; slot (ks+3)&3 free
    __builtin_amdgcn_sched_barrier(0);
    const int slotb = (ks & 3) << 14;
    bf16x8 af[8], bfr[4];
#pragma unroll
    for (int m = 0; m < 8; ++m)
      af[m] = *reinterpret_cast<const bf16x8*>((const char*)ldsA + slotb + aoff[m]);
#pragma unroll
    for (int n = 0; n < 4; ++n)
      bfr[n] = *reinterpret_cast<const bf16x8*>((const char*)ldsB + slotb + boff[n]);
    stage(ks + 3);  // prefetch 3 ahead; stays in flight across barriers
    __builtin_amdgcn_s_setprio(1);
#pragma unroll
    for (int m = 0; m < 8; ++m)
#pragma unroll
      for (int n = 0; n < 4; ++n)
        acc[m][n] = __builtin_amdgcn_mfma_f32_16x16x32_bf16(af[m], bfr[n],
                                                            acc[m][n], 0, 0, 0);
    __builtin_amdgcn_s_setprio(0);
  }

  // epilogue: D row=(lane>>4)*4+reg is p, col=lane&15 is cout
#pragma unroll
  for (int m = 0; m < 8; ++m) {
    const int p = p0 + wm * 128 + m * 16 + (lhi << 2);
#pragma unroll
    for (int n = 0; n < 4; ++n) {
      const int co = wn * 64 + n * 16 + l15;
      float* dst = out + ((size_t)(b * 256 + co) << 12) + p;
      *reinterpret_cast<f32x4*>(dst) = acc[m][n];
    }
  }
}

extern "C" void kernel_launch(void* const* d_in, const int* in_sizes, int n_in,
                              void* d_out, int out_size, void* d_ws, size_t ws_size,
                              hipStream_t stream) {
  const float* x = (const float*)d_in[0];
  const float* w1 = (const float*)d_in[1];
  const float* bng = (const float*)d_in[2];
  const float* bnb = (const float*)d_in[3];
  const float* bnm = (const float*)d_in[4];
  const float* bnv = (const float*)d_in[5];
  const float* w2 = (const float*)d_in[6];
  const float* wgt = (const float*)d_in[7];
  float* out = (float*)d_out;

  char* ws = (char*)d_ws;
  const size_t xtp_bytes = (size_t)16 * 4356 * 256 * 2;    // 35,684,352
  const size_t agg_bytes = (size_t)16 * 9 * 256 * 256 * 2; // 18,874,368
  unsigned short* xTp = (unsigned short*)ws;
  unsigned short* agg = (unsigned short*)(ws + xtp_bytes);
  float* pooled = (float*)(ws + xtp_bytes + agg_bytes);
  float* att = (float*)(ws + xtp_bytes + agg_bytes + 16384);

  hipMemsetAsync(pooled, 0, 16 * 256 * sizeof(float), stream);
  border_kernel<<<dim3(260, 16), 256, 0, stream>>>(xTp);
  transpose_kernel<<<1024, 256, 0, stream>>>(x, xTp, pooled);
  attn_kernel<<<1, 256, 0, stream>>>(pooled, w1, bng, bnb, bnm, bnv, w2, att);
  agg_kernel<<<4096, 256, 0, stream>>>(att, wgt, agg);
  conv_kernel<<<256, 512, 0, stream>>>(xTp, agg, out);
}